// Round 7
// baseline (603.192 us; speedup 1.0000x reference)
//
#include <hip/hip_runtime.h>

typedef float v2f __attribute__((ext_vector_type(2)));
typedef float v4f __attribute__((ext_vector_type(4)));

#define BATCH 2048
#define TSEQ 512
#define FUT 64
#define TOUT (TSEQ + FUT)   // 576
#define HID 50

// Block = 128 threads = 2 waves = ONE batch row.
// wave0 owns gate rows {i,f} = rows [0..49],[50..99]   of W_hh
// wave1 owns gate rows {g,o} = rows [100..149],[150..199]
// Per-lane weight footprint: 2 rows x 50 = 100 VGPRs (fits arch file).

__device__ __forceinline__ float rcp_f(float x) { return __builtin_amdgcn_rcpf(x); }
__device__ __forceinline__ float sigm(float x)  { return rcp_f(1.f + __expf(-x)); }
__device__ __forceinline__ float tanh_f(float x){ return 1.f - 2.f * rcp_f(__expf(2.f * x) + 1.f); }

// packed 2xf32 FMA: acc = a*b + acc  (VOP3P v_pk_fma_f32)
__device__ __forceinline__ void pkfma(v2f& acc, v2f a, v2f b) {
  asm("v_pk_fma_f32 %0, %1, %2, %0" : "+v"(acc) : "v"(a), "v"(b));
}

__global__ __launch_bounds__(128, 3) void lstm_seq_kernel(
    const float* __restrict__ x,      // [B, T]
    const float* __restrict__ W_ih,   // [200, 1]
    const float* __restrict__ W_hh,   // [200, 50]
    const float* __restrict__ b_ih,   // [200]
    const float* __restrict__ b_hh,   // [200]
    const float* __restrict__ W_out,  // [1, 50]
    const float* __restrict__ b_out,  // [1]
    float* __restrict__ out)          // [B, 576]
{
  __shared__ float sH[64];     // h broadcast (lanes >=50 hold 0)
  __shared__ v2f   sGb[HID];   // wave1 -> wave0: (tanh g, sigm o)
  __shared__ float sOut[1];    // prediction feedback for future phase
  __shared__ float sx[TSEQ];   // this row's input

  const int tid  = threadIdx.x;
  const int wv   = tid >> 6;          // 0 or 1
  const int lane = tid & 63;
  const int row  = blockIdx.x;

  for (int i = tid; i < TSEQ; i += 128) sx[i] = x[row * TSEQ + i];
  if (tid < 64) sH[tid] = 0.f;

  const bool act = (lane < HID);
  const int  kk  = act ? lane : 0;
  const int  rA  = (2 * wv) * HID + kk;       // i (wv0) / g (wv1)
  const int  rB  = (2 * wv + 1) * HID + kk;   // f (wv0) / o (wv1)

  // one-time weight load, global -> registers (rows are 8B-aligned: 200B stride)
  v2f wA[25], wB[25];
  {
    const v2f* pA = (const v2f*)(W_hh + rA * HID);
    const v2f* pB = (const v2f*)(W_hh + rB * HID);
    #pragma unroll
    for (int j = 0; j < 25; ++j) { wA[j] = pA[j]; wB[j] = pB[j]; }
  }
  const float bA  = b_ih[rA] + b_hh[rA];
  const float bB  = b_ih[rB] + b_hh[rB];
  const float wxA = W_ih[rA];
  const float wxB = W_ih[rB];
  const float wout = act ? W_out[kk] : 0.f;
  const float bout = b_out[0];

  float c = 0.f;                       // cell state lives ONLY in wave0
  float* orow = out + (size_t)row * TOUT;
  const v4f* sH4 = (const v4f*)sH;
  const v2f* sH2 = (const v2f*)sH;

  __syncthreads();

  #pragma unroll 1
  for (int t = 0; t < TOUT; ++t) {
    // xv: teacher-forced from sx, else previous prediction (valid after barrier2)
    const float xv = (t < TSEQ) ? sx[t] : sOut[0];

    // ---- phase A (both waves): 2 gate pre-activations over K=50 ----
    v2f aA = {fmaf(xv, wxA, bA), 0.f};
    v2f aB = {fmaf(xv, wxB, bB), 0.f};
    #pragma unroll
    for (int q = 0; q < 12; ++q) {     // m = 0..47, uniform b128 broadcast reads
      v4f h4 = sH4[q];
      v2f ha = {h4.x, h4.y}, hb = {h4.z, h4.w};
      pkfma(aA, wA[2 * q], ha); pkfma(aA, wA[2 * q + 1], hb);
      pkfma(aB, wB[2 * q], ha); pkfma(aB, wB[2 * q + 1], hb);
    }
    { v2f ht = sH2[24]; pkfma(aA, wA[24], ht); pkfma(aB, wB[24], ht); }  // m=48,49
    const float pa = aA.x + aA.y;
    const float pb = aB.x + aB.y;

    v2f gp;
    if (wv == 0) gp = (v2f){sigm(pa),  sigm(pb)};   // (sig i, sig f)
    else         gp = (v2f){tanh_f(pa), sigm(pb)};  // (tanh g, sig o)
    if (wv == 1 && act) sGb[kk] = gp;
    __syncthreads();                                 // barrier 1: sGb ready

    // ---- phase B (wave0 only): combine, state update, output ----
    if (wv == 0) {
      const v2f go = sGb[kk];                        // (tanh g, sig o)
      c = fmaf(gp.y, c, gp.x * go.x);                // c = f*c + i*g
      const float h = act ? go.y * tanh_f(c) : 0.f;  // h = o * tanh(c)
      sH[lane] = h;                                  // broadcast for next step
      float p = h * wout;                            // out = sum h[k] W_out[k] + b
      p += __shfl_xor(p, 1);
      p += __shfl_xor(p, 2);
      p += __shfl_xor(p, 4);
      p += __shfl_xor(p, 8);
      p += __shfl_xor(p, 16);
      p += __shfl_xor(p, 32);
      const float ot = p + bout;
      if (lane == 0) { orow[t] = ot; sOut[0] = ot; }
    }
    __syncthreads();                                 // barrier 2: sH/sOut ready
  }
}

extern "C" void kernel_launch(void* const* d_in, const int* in_sizes, int n_in,
                              void* d_out, int out_size, void* d_ws, size_t ws_size,
                              hipStream_t stream) {
  const float* x     = (const float*)d_in[0];
  const float* W_ih  = (const float*)d_in[1];
  const float* W_hh  = (const float*)d_in[2];
  const float* b_ih  = (const float*)d_in[3];
  const float* b_hh  = (const float*)d_in[4];
  const float* W_out = (const float*)d_in[5];
  const float* b_out = (const float*)d_in[6];
  float* out = (float*)d_out;

  lstm_seq_kernel<<<BATCH, 128, 0, stream>>>(
      x, W_ih, W_hh, b_ih, b_hh, W_out, b_out, out);
}